// Round 6
// baseline (3257.174 us; speedup 1.0000x reference)
//
#include <hip/hip_runtime.h>

#ifndef M_PI
#define M_PI 3.14159265358979323846
#endif

#define T_DATA 20000
#define E_NO_C 2000
#define I_NO_C 500
#define SUB 16
#define TNO 200
#define NGRP 2500   // groups of 8 steps

typedef float v2f __attribute__((ext_vector_type(2)));

// ---------------- Kernel A: filter kernels (e, i, spk, hist) -> d_out[320000..] ----------------
__global__ void filters_k(const float* __restrict__ Tau_e, const float* __restrict__ Tau_i,
                          const float* __restrict__ W_e,  const float* __restrict__ W_i,
                          const float* __restrict__ D_e,  const float* __restrict__ D_i,
                          const float* __restrict__ Tau_spk, const float* __restrict__ W_spk,
                          const float* __restrict__ W_hist,
                          float* __restrict__ filt_out) {
  int id = blockIdx.x * blockDim.x + threadIdx.x;
  if (id >= 64 * TNO) return;
  int r = id / TNO, x = id % TNO;
  int s = r & 15, kind = r >> 4;
  double xd = (double)x;
  double val;
  if (kind == 0) {
    double te = xd - exp((double)D_e[s]); te = te > 0.0 ? te : 0.0;
    double tt = te / exp((double)Tau_e[s]);
    val = tt * exp(-tt) * exp((double)W_e[s]);
  } else if (kind == 1) {
    double ti = xd - exp((double)D_i[s]); ti = ti > 0.0 ? ti : 0.0;
    double tt = ti / exp((double)Tau_i[s]);
    val = -tt * exp(-tt) * exp((double)W_i[s]);
  } else if (kind == 2) {
    double tt = xd / exp((double)Tau_spk[s]);
    val = tt * exp(-tt) * exp((double)W_spk[s]);
  } else {
    double raw = 4.0 * log(xd + 1.0);
    double acc = 0.0;
    for (int i = 0; i < 16; ++i) {
      double phi = (M_PI / 2.0) * (double)i;
      double b = (raw < phi - M_PI || raw > phi + M_PI) ? 0.0
                                                        : (0.5 * cos(raw - phi) + 0.5);
      acc += (double)W_hist[s * 16 + i] * b;
    }
    val = acc;
  }
  filt_out[id] = (float)val;
}

// ---------------- Kernel B: syn = S @ C^T, C staged in LDS tiles ----------------
#define ETILE 500
__global__ __launch_bounds__(256) void synmm_k(const float* __restrict__ S,
                                               const float* __restrict__ C,
                                               float* __restrict__ out, int E) {
  __shared__ __align__(16) float Cs[16][ETILE];
  int tid = threadIdx.x;
  int s = tid & 15, tt = tid >> 4;
  long t = (long)blockIdx.x * 16 + tt;
  const float* Srow = S + t * E;
  float acc = 0.f;
  for (int tb = 0; tb < E; tb += ETILE) {
    __syncthreads();
    for (int i = tid; i < 16 * ETILE; i += 256) {
      int s2 = i / ETILE, k2 = i - s2 * ETILE;
      Cs[s2][k2] = C[(long)s2 * E + tb + k2];
    }
    __syncthreads();
    const float* Crow = &Cs[s][0];
    const float* Sp = Srow + tb;
#pragma unroll 2
    for (int e = 0; e < ETILE; e += 4) {
      float4 a = *(const float4*)(Sp + e);
      float4 c = *(const float4*)(Crow + e);
      acc = fmaf(a.x, c.x, acc); acc = fmaf(a.y, c.y, acc);
      acc = fmaf(a.z, c.z, acc); acc = fmaf(a.w, c.w, acc);
    }
  }
  out[t * 16 + s] = acc;
}

// ---------------- Kernel C: causal depthwise conv + Theta, TRANSPOSED output ----------------
__global__ void conv_k(const float* __restrict__ syn_e, const float* __restrict__ syn_i,
                       const float* __restrict__ filt, const float* __restrict__ Theta,
                       float* __restrict__ synT) {
  __shared__ float ek[16][201];
  __shared__ float ik[16][201];
  int tid = threadIdx.x;
  for (int idx = tid; idx < 16 * TNO; idx += 256) {
    ek[idx / TNO][idx % TNO] = filt[idx];
    ik[idx / TNO][idx % TNO] = filt[16 * TNO + idx];
  }
  __syncthreads();
  int s = tid & 15, tt = tid >> 4;
  int t = blockIdx.x * 16 + tt;
  float acc = Theta[s];
  if (t >= TNO) {
#pragma unroll 4
    for (int j = 0; j < TNO; ++j) {
      int u = t - 1 - j;
      acc += ek[s][j] * syn_e[u * 16 + s] + ik[s][j] * syn_i[u * 16 + s];
    }
  } else {
    for (int j = 0; j < t; ++j) {
      int u = t - 1 - j;
      acc += ek[s][j] * syn_e[u * 16 + s] + ik[s][j] * syn_i[u * 16 + s];
    }
  }
  synT[(long)s * T_DATA + t] = acc;
}

// ---------------- Kernel D: 8-step groups, lag-1 gather, dot-form mid region ----------------
// Wave 0 (scan), per 8-step iter: 12 oPart reads (hidden) + 8 mid dots (delays K+1..K+8
//   from prev[] regs) + per-step {pend+mix add, delay-1 fma, cmp, ballot, IIR} + 21
//   in-group scatter fmas (delays 2..7, >=2-step slack). No global stores.
// Waves 1-3 (gather): group I+1, delays >= K+9 (window ends time 8I-1, barrier-visible);
//   64 pk_fma, ONE shuffle level, write 2 half-partials. Wave 1 also stores spk_out for
//   group I-1 from the ring (coalesced).
__global__ __launch_bounds__(256, 1) void scan5_k(const float* __restrict__ synT,
                                                  const float* __restrict__ filt,
                                                  const float* __restrict__ C_den,
                                                  const float* __restrict__ Tau_spk,
                                                  const float* __restrict__ W_spk,
                                                  float* __restrict__ spk_out) {
  __shared__ __align__(16) float ring[16][452];        // [s][pos], mirror pos+256 for pos<192
  __shared__ __align__(16) float oPart[2][3][2][16][8]; // [slot][w][half][s][K]
  const int tid = threadIdx.x;
  const int widx = tid >> 6;
  const int l = tid & 63;
  const int s = l & 15, q = l >> 4;

  for (int i = tid; i < 16 * 452; i += 256) (&ring[0][0])[i] = 0.f;
  for (int i = tid; i < 2 * 3 * 2 * 16 * 8; i += 256) (&oPart[0][0][0][0][0])[i] = 0.f;
  __syncthreads();

  if (widx == 0) {
    // ================= scan wave =================
    const float* hrow = filt + (48 + s) * TNO;
    float hk[15];
#pragma unroll
    for (int i = 0; i < 15; ++i) hk[i] = hrow[i];

    float t0v = Tau_spk[0], w0v = W_spk[0];
    bool okrow = (Tau_spk[s] == t0v) && (W_spk[s] == w0v);
    unsigned cd = 0u;
#pragma unroll
    for (int j = 0; j < 16; ++j) {
      float cv = C_den[s * 16 + j];
      okrow = okrow && (cv == 0.f || cv == 1.f);
      cd |= (cv != 0.f) ? (1u << j) : 0u;
    }
    const bool uni = (bool)__all((int)okrow);

    const double tau  = exp((double)Tau_spk[s]);
    const double aa   = exp(-1.0 / tau);
    const double c2a  = exp((double)W_spk[s]) * aa / tau;  // K[d]=C(d-1)a^(d-1), C=w/tau
    const double twoa = 2.0 * aa;
    const double na2  = -aa * aa;

    double twoa4[4], na24[4], c2a4[4], yd0a[4], yd1a[4];
    float cden4[4];
#pragma unroll
    for (int r = 0; r < 4; ++r) {
      int j = 4 * q + r;
      double tj = exp((double)Tau_spk[j]);
      double aj = exp(-1.0 / tj);
      twoa4[r] = 2.0 * aj; na24[r] = -aj * aj;
      c2a4[r]  = exp((double)W_spk[j]) * aj / tj;
      yd0a[r] = 0.0; yd1a[r] = 0.0;
      cden4[r] = C_den[s * 16 + j];
    }

    double zA = 0.0, zB = 0.0;
    float mixu = 0.f, mix1 = 0.f;
    float prev[8];                       // prev[d] = spike(8I-1-d, s)
#pragma unroll
    for (int i = 0; i < 8; ++i) prev[i] = 0.f;

    float4 sva = *(const float4*)(synT + (long)s * T_DATA + 0);
    float4 svb = *(const float4*)(synT + (long)s * T_DATA + 4);

#define STEP(K, D1)                                                           \
    {                                                                         \
      float pre = base[K] + (pend[K] + mixu);                                 \
      float sub = fmaf(hk[0], (D1), pre);                                     \
      unsigned long long bal = __ballot(sub > 0.f);                           \
      float sg = sub > 0.f ? 1.f : 0.f;                                       \
      unsigned mk = (unsigned)bal & 0xFFFFu;                                  \
      if (uni) {                                                              \
        double zc = fma(twoa, zB, fma(na2, zA, c2a * (double)__popc(mk & cd))); \
        zA = zB; zB = zc;                                                     \
        mixu = (float)zA;                                                     \
      } else {                                                                \
        float p = 0.f;                                                        \
        _Pragma("unroll")                                                     \
        for (int r = 0; r < 4; ++r) {                                         \
          double xr = (double)((mk >> (4 * q + r)) & 1u);                     \
          double y2 = fma(twoa4[r], yd1a[r], fma(na24[r], yd0a[r], c2a4[r] * xr)); \
          yd0a[r] = yd1a[r]; yd1a[r] = y2;                                    \
          p = fmaf(cden4[r], (float)y2, p);                                   \
        }                                                                     \
        p += __shfl_xor(p, 16); p += __shfl_xor(p, 32);                       \
        float mixn = mix1; mix1 = p;                                          \
        mixu = mixn;                                                          \
      }                                                                       \
      _Pragma("unroll")                                                       \
      for (int dd = 2; dd < 8; ++dd)                                          \
        if ((K) + dd < 8) pend[(K) + dd] = fmaf(hk[dd - 1], sg, pend[(K) + dd]); \
      S[(K)] = sg;                                                            \
    }

    for (int I = 0; I < NGRP; ++I) {
      const int sl = I & 1;
      float4 rA[3][2], rB[3][2];
#pragma unroll
      for (int w = 0; w < 3; ++w)
#pragma unroll
        for (int h = 0; h < 2; ++h) {
          rA[w][h] = *(const float4*)&oPart[sl][w][h][s][0];
          rB[w][h] = *(const float4*)&oPart[sl][w][h][s][4];
        }
      float4 svna, svnb;
      if (I + 1 < NGRP) {
        svna = *(const float4*)(synT + (long)s * T_DATA + 8 * (I + 1));
        svnb = *(const float4*)(synT + (long)s * T_DATA + 8 * (I + 1) + 4);
      } else {
        svna.x = svna.y = svna.z = svna.w = 0.f;
        svnb.x = svnb.y = svnb.z = svnb.w = 0.f;
      }

      // mid dots: delays K+1..K+8 from prev[] (K=0 skips d=0: delay-1 lives on the chain)
      float mid[8];
#pragma unroll
      for (int K = 0; K < 8; ++K) {
        float m = 0.f;
#pragma unroll
        for (int d = 0; d < 8; ++d) {
          if (K == 0 && d == 0) continue;
          m = fmaf(hk[K + d], prev[d], m);
        }
        mid[K] = m;
      }

      float oc_[8];
#pragma unroll
      for (int K = 0; K < 4; ++K) {
        const float* fA = (const float*)&rA[0][0];
        // manual component sums (K indexes float4 component)
        oc_[K] = (((&rA[0][0].x)[K] + (&rA[0][1].x)[K]) +
                  ((&rA[1][0].x)[K] + (&rA[1][1].x)[K])) +
                  ((&rA[2][0].x)[K] + (&rA[2][1].x)[K]);
        oc_[K + 4] = (((&rB[0][0].x)[K] + (&rB[0][1].x)[K]) +
                      ((&rB[1][0].x)[K] + (&rB[1][1].x)[K])) +
                      ((&rB[2][0].x)[K] + (&rB[2][1].x)[K]);
        (void)fA;
      }

      float base[8];
      base[0] = (mid[0] + oc_[0]) + sva.x;
      base[1] = (mid[1] + oc_[1]) + sva.y;
      base[2] = (mid[2] + oc_[2]) + sva.z;
      base[3] = (mid[3] + oc_[3]) + sva.w;
      base[4] = (mid[4] + oc_[4]) + svb.x;
      base[5] = (mid[5] + oc_[5]) + svb.y;
      base[6] = (mid[6] + oc_[6]) + svb.z;
      base[7] = (mid[7] + oc_[7]) + svb.w;

      float pend[8];
#pragma unroll
      for (int i = 0; i < 8; ++i) pend[i] = 0.f;
      float S[8];

      STEP(0, prev[0])
      STEP(1, S[0])
      STEP(2, S[1])
      STEP(3, S[2])
      STEP(4, S[3])
      STEP(5, S[4])
      STEP(6, S[5])
      STEP(7, S[6])

      if (l < 16) {
        int u = (8 * I) & 255;
        float4 w0; w0.x = S[0]; w0.y = S[1]; w0.z = S[2]; w0.w = S[3];
        float4 w1; w1.x = S[4]; w1.y = S[5]; w1.z = S[6]; w1.w = S[7];
        *(float4*)&ring[s][u] = w0;
        *(float4*)&ring[s][u + 4] = w1;
        if (u <= 184) {
          *(float4*)&ring[s][u + 256] = w0;
          *(float4*)&ring[s][u + 260] = w1;
        }
      }
#pragma unroll
      for (int d = 0; d < 8; ++d) prev[d] = S[7 - d];
      sva = svna; svb = svnb;
      __syncthreads();
    }
#undef STEP
  } else {
    // ================= gather waves (w = 0..2), group I+1, delays >= K+9 =================
    const int w = widx - 1;
    const int g = w * 4 + q;                 // lane-group 0..11, 16 positions each
    const float* hrow = filt + (48 + s) * TNO;
    float ca[23];
#pragma unroll
    for (int n = 0; n < 23; ++n) {
      int idx = 184 - 16 * g + n;            // coeff idx for window pos B+16g+i, n=15+K-i
      ca[n] = (idx <= 199) ? hrow[idx] : 0.f;
    }
    v2f pr[23];
    pr[0].x = 0.f; pr[0].y = 0.f;
#pragma unroll
    for (int m = 1; m < 23; ++m) { pr[m].x = ca[m]; pr[m].y = ca[m - 1]; }

    for (int I = 0; I < NGRP; ++I) {
      int Pe = (8 * I - 1) & 255;            // window end = time 8I-1
      if (Pe < 191) Pe += 256;               // mirrored tail keeps window contiguous
      const float4* rp = (const float4*)&ring[s][(Pe - 191) + 16 * g];
      float4 V0 = rp[0], V1 = rp[1], V2 = rp[2], V3 = rp[3];

      v2f aE[8], aO[8];
#pragma unroll
      for (int K = 0; K < 8; ++K) {
        aE[K].x = 0.f; aE[K].y = 0.f; aO[K].x = 0.f; aO[K].y = 0.f;
      }
#define GMAC(V, J, ACC)                                   \
      { v2f A;  A.x  = (V).x; A.y  = (V).y;               \
        v2f Bv; Bv.x = (V).z; Bv.y = (V).w;               \
        _Pragma("unroll")                                 \
        for (int K = 0; K < 8; ++K) {                     \
          ACC[K] += pr[15 + K - 4 * (J)] * A;             \
          ACC[K] += pr[13 + K - 4 * (J)] * Bv;            \
        } }
      GMAC(V0, 0, aE) GMAC(V1, 1, aO) GMAC(V2, 2, aE) GMAC(V3, 3, aO)
#undef GMAC
      float o[8];
#pragma unroll
      for (int K = 0; K < 8; ++K) {
        v2f t = aE[K] + aO[K];
        float v = t.x + t.y;
        v += __shfl_xor(v, 16);              // one level: q-pairs (0+1), (2+3)
        o[K] = v;
      }
      if ((q & 1) == 0) {
        int h = q >> 1;
        float4 pa; pa.x = o[0]; pa.y = o[1]; pa.z = o[2]; pa.w = o[3];
        float4 pb; pb.x = o[4]; pb.y = o[5]; pb.z = o[6]; pb.w = o[7];
        *(float4*)&oPart[(I + 1) & 1][w][h][s][0] = pa;
        *(float4*)&oPart[(I + 1) & 1][w][h][s][4] = pb;
      }
      if (w == 1 && I > 0) {
        // store spikes of group I-1 (ring positions written last iter, stable)
        int u = (8 * (I - 1)) & 255;
        spk_out[(long)(I - 1) * 128 + l]      = ring[s][u + q];
        spk_out[(long)(I - 1) * 128 + 64 + l] = ring[s][u + 4 + q];
      }
      __syncthreads();
    }
    if (w == 1) {                            // tail: last group's spikes
      int u = (8 * (NGRP - 1)) & 255;
      spk_out[(long)(NGRP - 1) * 128 + l]      = ring[s][u + q];
      spk_out[(long)(NGRP - 1) * 128 + 64 + l] = ring[s][u + 4 + q];
    }
  }
}

extern "C" void kernel_launch(void* const* d_in, const int* in_sizes, int n_in,
                              void* d_out, int out_size, void* d_ws, size_t ws_size,
                              hipStream_t stream) {
  const float* S_e     = (const float*)d_in[0];
  const float* S_i     = (const float*)d_in[1];
  const float* C_den   = (const float*)d_in[2];
  const float* C_syn_e = (const float*)d_in[3];
  const float* C_syn_i = (const float*)d_in[4];
  const float* Tau_e   = (const float*)d_in[5];
  const float* Tau_i   = (const float*)d_in[6];
  const float* W_e     = (const float*)d_in[7];
  const float* W_i     = (const float*)d_in[8];
  const float* D_e     = (const float*)d_in[9];
  const float* D_i     = (const float*)d_in[10];
  const float* Tau_spk = (const float*)d_in[11];
  const float* W_spk   = (const float*)d_in[12];
  const float* W_hist  = (const float*)d_in[13];
  const float* Theta   = (const float*)d_in[14];

  float* out     = (float*)d_out;
  float* spk_out = out;            // 20000*16
  float* filt    = out + 320000;   // 64*200

  float* ws    = (float*)d_ws;
  float* syn_e = ws;               // 320000
  float* syn_i = ws + 320000;      // 320000
  float* synT  = ws + 640000;      // 320000 (transposed [s][t])

  filters_k<<<50, 256, 0, stream>>>(Tau_e, Tau_i, W_e, W_i, D_e, D_i,
                                    Tau_spk, W_spk, W_hist, filt);
  synmm_k<<<1250, 256, 0, stream>>>(S_e, C_syn_e, syn_e, E_NO_C);
  synmm_k<<<1250, 256, 0, stream>>>(S_i, C_syn_i, syn_i, I_NO_C);
  conv_k<<<1250, 256, 0, stream>>>(syn_e, syn_i, filt, Theta, synT);
  scan5_k<<<1, 256, 0, stream>>>(synT, filt, C_den, Tau_spk, W_spk, spk_out);
}